// Round 11
// baseline (108.536 us; speedup 1.0000x reference)
//
#include <hip/hip_runtime.h>

#define N_NODES 50000
#define N_EDGES 800000
#define DIM 100

#define SB_COUNT 98         // super-buckets of 512 nodes (dst>>9)
#define CAP1     8704       // records per super-bucket region (mean 8163, +6 sigma)
#define NB       1563       // final buckets of 32 nodes (dst>>5)
#define NBP      1568       // padded: 98*16
#define CAPB     768        // records per final bucket (mean 512, +11 sigma)
#define OVF_CAP  4096
#define EPB1     8192       // edges per bin1 block -> 98 blocks
#define GEMM_BLOCKS 1250    // 50000/40
#define ROWS_PB  40

// ---------------- workspace layout (bytes) ----------------
#define HIDB_OFF  0u            // bf16 hidden, packed uint[50000*50]   10,000,000
#define G1_OFF    10000448u     // int gcur1[98]
#define OVFC_OFF  10000448u+512u // int ovf_cnt
#define CNT2_OFF  10001024u     // int cnt2[1568]
#define OVF_OFF   10007296u     // int4 ovf[4096]
#define BKT1_OFF  10072832u     // uint2 bkt1[98*8704]                   6,823,936
#define BKT2_OFF  16896768u     // uint2 bkt2[1568*768]                  9,633,792
#define WT_OFF    26530560u     // float Wt[100*100]                        40,000
#define WS_NEED   26570560u

// float->bf16 RNE helpers
__device__ inline unsigned bf16hi(float v) {            // bf16 in HIGH 16 bits
    unsigned u = __float_as_uint(v);
    u += 0x7FFFu + ((u >> 16) & 1u);
    return u & 0xFFFF0000u;
}
__device__ inline unsigned bf16pair(float lo, float hi) {
    unsigned ulo = __float_as_uint(lo); ulo += 0x7FFFu + ((ulo >> 16) & 1u);
    unsigned uhi = __float_as_uint(hi); uhi += 0x7FFFu + ((uhi >> 16) & 1u);
    return (ulo >> 16) | (uhi & 0xFFFF0000u);
}

// ---------------- transpose + control-buffer zeroing ----------------
__global__ __launch_bounds__(256) void srgnn_transpose(
    const float* __restrict__ W, float* __restrict__ Wt,
    int* __restrict__ gcur1, int* __restrict__ ovfc)
{
    const unsigned i = blockIdx.x * 256u + threadIdx.x;
    if (i < DIM * DIM) {
        const int c = i / DIM, k = i - c * DIM;
        Wt[k * DIM + c] = W[i];
    }
    if (i < SB_COUNT) gcur1[i] = 0;
    if (i == 0) *ovfc = 0;
}

// ---------------- GEMM: hidden(bf16) = x @ W^T + b ----------------
__global__ __launch_bounds__(256) void srgnn_gemm2b(
    const float* __restrict__ x, const float* __restrict__ Wt,
    const float* __restrict__ b, unsigned* __restrict__ hidU)
{
    __shared__ float xs[ROWS_PB][DIM];   // 16 KB
    const int t = threadIdx.x;
    const int row0 = blockIdx.x * ROWS_PB;

    for (int i = t; i < ROWS_PB * 25; i += 256) {
        const int r = i / 25, c4 = (i - r * 25) * 4;
        const float4 v = *reinterpret_cast<const float4*>(
            &x[(size_t)(row0 + r) * DIM + c4]);
        *reinterpret_cast<float4*>(&xs[r][c4]) = v;
    }
    __syncthreads();

    if (t < 250) {
        const int g  = t / 25;            // row group 0..9
        const int c4 = (t - g * 25) * 4;  // col chunk
        const float4 bv = *reinterpret_cast<const float4*>(&b[c4]);
        float4 a0 = bv, a1 = bv, a2 = bv, a3 = bv;

        #pragma unroll 4
        for (int k = 0; k < DIM; ++k) {
            const float4 wv = *reinterpret_cast<const float4*>(&Wt[k * DIM + c4]);
            const float x0 = xs[g     ][k];
            const float x1 = xs[g + 10][k];
            const float x2 = xs[g + 20][k];
            const float x3 = xs[g + 30][k];
            a0.x += x0 * wv.x; a0.y += x0 * wv.y; a0.z += x0 * wv.z; a0.w += x0 * wv.w;
            a1.x += x1 * wv.x; a1.y += x1 * wv.y; a1.z += x1 * wv.z; a1.w += x1 * wv.w;
            a2.x += x2 * wv.x; a2.y += x2 * wv.y; a2.z += x2 * wv.z; a2.w += x2 * wv.w;
            a3.x += x3 * wv.x; a3.y += x3 * wv.y; a3.z += x3 * wv.z; a3.w += x3 * wv.w;
        }
        const int u0 = c4 >> 1;           // uint index within row
        uint2 p;
        p.x = bf16pair(a0.x, a0.y); p.y = bf16pair(a0.z, a0.w);
        *reinterpret_cast<uint2*>(&hidU[(size_t)(row0 + g     ) * 50 + u0]) = p;
        p.x = bf16pair(a1.x, a1.y); p.y = bf16pair(a1.z, a1.w);
        *reinterpret_cast<uint2*>(&hidU[(size_t)(row0 + g + 10) * 50 + u0]) = p;
        p.x = bf16pair(a2.x, a2.y); p.y = bf16pair(a2.z, a2.w);
        *reinterpret_cast<uint2*>(&hidU[(size_t)(row0 + g + 20) * 50 + u0]) = p;
        p.x = bf16pair(a3.x, a3.y); p.y = bf16pair(a3.z, a3.w);
        *reinterpret_cast<uint2*>(&hidU[(size_t)(row0 + g + 30) * 50 + u0]) = p;
    }
}

// ---------------- bin1: edges -> 98 super-buckets of 512 nodes ------------
// Runs of ~83 records (668B) per (block,SB): stores are dense & temporally
// local -> near-zero line-writeback amplification.
__global__ __launch_bounds__(512) void srgnn_bin1(
    const int* __restrict__ esrc, const int* __restrict__ edst,
    const float* __restrict__ ew, int* __restrict__ gcur1,
    int* __restrict__ ovfc, int4* __restrict__ ovf, uint2* __restrict__ bkt1)
{
    __shared__ int hist[SB_COUNT];
    __shared__ int lcur[SB_COUNT];
    const int t = threadIdx.x;
    const int e0 = blockIdx.x * EPB1;

    for (int i = t; i < SB_COUNT; i += 512) hist[i] = 0;
    __syncthreads();

    int d[16];
    #pragma unroll
    for (int k = 0; k < 16; ++k) {
        const int e = e0 + t + k * 512;
        d[k] = (e < N_EDGES) ? edst[e] : -1;
        if (d[k] >= 0) atomicAdd(&hist[d[k] >> 9], 1);
    }
    __syncthreads();
    for (int i = t; i < SB_COUNT; i += 512)
        if (hist[i]) lcur[i] = atomicAdd(&gcur1[i], hist[i]);
    __syncthreads();
    #pragma unroll
    for (int k = 0; k < 16; ++k) {
        if (d[k] >= 0) {
            const int e = e0 + t + k * 512;
            const int s = esrc[e];
            const float w = ew[e];
            const int sb = d[k] >> 9;
            const int pos = atomicAdd(&lcur[sb], 1);
            if (pos < CAP1) {
                bkt1[(size_t)sb * CAP1 + pos] =
                    make_uint2((unsigned)s | bf16hi(w), (unsigned)d[k]);
            } else {
                const int op = atomicAdd(ovfc, 1);
                if (op < OVF_CAP) ovf[op] = make_int4(d[k], s, __float_as_int(w), 0);
            }
        }
    }
}

// ---------------- bin2: super-bucket -> 16 final 32-node buckets ----------
// Block sb reads its CONTIGUOUS bkt1 region twice (hist pass + place pass,
// both coalesced). Each final bucket gets ONE ~4KB contiguous run -> zero
// write amplification. Replicated (x8) LDS counters kill atomic contention.
__global__ __launch_bounds__(512) void srgnn_bin2(
    const int* __restrict__ gcur1, const uint2* __restrict__ bkt1,
    int* __restrict__ cnt2, int* __restrict__ ovfc, int4* __restrict__ ovf,
    uint2* __restrict__ bkt2)
{
    __shared__ int histr[8][16];   // replicated hist / reused as cursors
    const int t = threadIdx.x;
    const int sb = blockIdx.x;
    const int rep = t & 7;

    int cnt = gcur1[sb];
    if (cnt > CAP1) cnt = CAP1;

    if (t < 128) histr[t >> 4][t & 15] = 0;
    __syncthreads();

    for (int i = t; i < cnt; i += 512) {
        const uint2 r = bkt1[(size_t)sb * CAP1 + i];
        atomicAdd(&histr[rep][(r.y >> 5) & 15], 1);
    }
    __syncthreads();

    // thread j<16: totals + per-replica bases; cursors written back in place
    if (t < 16) {
        int tot = 0;
        int base[8];
        #pragma unroll
        for (int r = 0; r < 8; ++r) { base[r] = tot; tot += histr[r][t]; }
        #pragma unroll
        for (int r = 0; r < 8; ++r) histr[r][t] = base[r];
        cnt2[sb * 16 + t] = (tot < CAPB) ? tot : CAPB;
    }
    __syncthreads();

    for (int i = t; i < cnt; i += 512) {
        const uint2 r = bkt1[(size_t)sb * CAP1 + i];
        const int j = (r.y >> 5) & 15;
        const int pos = atomicAdd(&histr[rep][j], 1);
        if (pos < CAPB) {
            bkt2[(size_t)(sb * 16 + j) * CAPB + pos] = r;
        } else {
            const int op = atomicAdd(ovfc, 1);
            if (op < OVF_CAP)
                ovf[op] = make_int4((int)r.y, (int)(r.x & 0xFFFFu),
                                    (int)(r.x & 0xFFFF0000u), 0);
        }
    }
}

// ---------------- aggregate: block per 32-node bucket, LDS counting sort --
__global__ __launch_bounds__(256) void srgnn_agg_s32(
    const unsigned* __restrict__ hidU, const int* __restrict__ cnt2,
    const uint2* __restrict__ bkt2, const int* __restrict__ ovfc,
    const int4* __restrict__ ovf, float* __restrict__ out)
{
    __shared__ uint2    recs[CAPB];     // 6144 B
    __shared__ unsigned srt[CAPB];      // 3072 B
    __shared__ int nh[32], sc[32], cur[32];

    const int t = threadIdx.x;
    const int bq = blockIdx.x;
    int cntb = cnt2[bq];
    if (cntb > CAPB) cntb = CAPB;

    if (t < 32) nh[t] = 0;
    __syncthreads();
    for (int i = t; i < cntb; i += 256) {
        const uint2 r = bkt2[(size_t)bq * CAPB + i];
        recs[i] = r;
        atomicAdd(&nh[r.y & 31], 1);
    }
    __syncthreads();
    if (t < 32) sc[t] = nh[t];
    __syncthreads();
    for (int ofs = 1; ofs < 32; ofs <<= 1) {         // Hillis-Steele inclusive
        int a = 0;
        if (t < 32 && t >= ofs) a = sc[t - ofs];
        __syncthreads();
        if (t < 32) sc[t] += a;
        __syncthreads();
    }
    if (t < 32) cur[t] = sc[t] - nh[t];
    __syncthreads();
    for (int i = t; i < cntb; i += 256) {
        const uint2 r = recs[i];
        const int pos = atomicAdd(&cur[r.y & 31], 1);
        srt[pos] = r.x;                              // src | bf16(w)<<16
    }
    __syncthreads();

    int oc = *ovfc;                                  // ~always 0
    if (oc > OVF_CAP) oc = OVF_CAP;
    const int lane = t & 63;
    const int wid  = t >> 6;                         // 4 waves
    const bool active = (lane < 50);

    for (int q = 0; q < 8; ++q) {
        const int n  = wid * 8 + q;                  // 4 waves x 8 = 32 nodes
        const int s1 = sc[n];
        const int s0 = s1 - nh[n];
        float2 acc = make_float2(0.f, 0.f);

        int p = s0;
        for (; p + 8 <= s1; p += 8) {                // 8-deep MLP
            unsigned r[8], h[8];
            #pragma unroll
            for (int j = 0; j < 8; ++j) r[j] = srt[p + j];
            if (active) {
                #pragma unroll
                for (int j = 0; j < 8; ++j)
                    h[j] = hidU[(size_t)(r[j] & 0xFFFFu) * 50 + lane];
                #pragma unroll
                for (int j = 0; j < 8; ++j) {
                    const float wj = __uint_as_float(r[j] & 0xFFFF0000u);
                    acc.x += wj * __uint_as_float(h[j] << 16);
                    acc.y += wj * __uint_as_float(h[j] & 0xFFFF0000u);
                }
            }
        }
        for (; p < s1; ++p) {
            const unsigned r = srt[p];
            const float wi = __uint_as_float(r & 0xFFFF0000u);
            if (active) {
                const unsigned h = hidU[(size_t)(r & 0xFFFFu) * 50 + lane];
                acc.x += wi * __uint_as_float(h << 16);
                acc.y += wi * __uint_as_float(h & 0xFFFF0000u);
            }
        }

        const int ng = bq * 32 + n;
        if (oc > 0) {                                // ultra-rare overflow scan
            for (int i = 0; i < oc; ++i) {
                const int4 v = ovf[i];
                if (v.x == ng && active) {
                    const unsigned h = hidU[(size_t)v.y * 50 + lane];
                    const float wi = __uint_as_float((unsigned)v.z);
                    acc.x += wi * __uint_as_float(h << 16);
                    acc.y += wi * __uint_as_float(h & 0xFFFF0000u);
                }
            }
        }
        if (ng < N_NODES && active)
            *reinterpret_cast<float2*>(&out[(size_t)ng * DIM + 2 * lane]) = acc;
    }
}

// ---------------- fallback (atomic scatter, needs only 20MB ws) ----------
__global__ __launch_bounds__(256) void srgnn_gemm_bias(
    const float* __restrict__ x, const float* __restrict__ W,
    const float* __restrict__ b, float* __restrict__ hidden)
{
    __shared__ float Wt[DIM][DIM + 4];
    __shared__ float bs[DIM];
    __shared__ float xs[8][DIM];
    const int t = threadIdx.x;
    for (int i = t; i < DIM * DIM; i += 256) {
        int c = i / DIM, k = i - c * DIM;
        Wt[k][c] = W[i];
    }
    if (t < DIM) bs[t] = b[t];
    const int row0 = blockIdx.x * 8;
    for (int i = t; i < 8 * DIM; i += 256) {
        int r = i / DIM, k = i - r * DIM;
        int row = row0 + r;
        xs[r][k] = (row < N_NODES) ? x[row * DIM + k] : 0.0f;
    }
    __syncthreads();
    if (t < 200) {
        const int r  = t / 25;
        const int c4 = (t - r * 25) * 4;
        float acc0 = bs[c4 + 0], acc1 = bs[c4 + 1], acc2 = bs[c4 + 2], acc3 = bs[c4 + 3];
        for (int k = 0; k < DIM; ++k) {
            const float xv = xs[r][k];
            const float4 wv = *reinterpret_cast<const float4*>(&Wt[k][c4]);
            acc0 += xv * wv.x; acc1 += xv * wv.y; acc2 += xv * wv.z; acc3 += xv * wv.w;
        }
        const int row = row0 + r;
        if (row < N_NODES)
            *reinterpret_cast<float4*>(&hidden[row * DIM + c4]) =
                make_float4(acc0, acc1, acc2, acc3);
    }
}

__global__ __launch_bounds__(256) void srgnn_scatter_atomic(
    const float* __restrict__ hidden, const int* __restrict__ esrc,
    const int* __restrict__ edst, const float* __restrict__ ew,
    float* __restrict__ out)
{
    const unsigned gid = blockIdx.x * 256u + threadIdx.x;
    const unsigned e = gid / 25u;
    const unsigned j = gid - e * 25u;
    if (e >= N_EDGES) return;
    const int   s  = esrc[e];
    const int   d  = edst[e];
    const float wt = ew[e];
    const float4 h = *reinterpret_cast<const float4*>(&hidden[(size_t)s * DIM + j * 4]);
    float* op = &out[(size_t)d * DIM + j * 4];
    atomicAdd(op + 0, h.x * wt);
    atomicAdd(op + 1, h.y * wt);
    atomicAdd(op + 2, h.z * wt);
    atomicAdd(op + 3, h.w * wt);
}

extern "C" void kernel_launch(void* const* d_in, const int* in_sizes, int n_in,
                              void* d_out, int out_size, void* d_ws, size_t ws_size,
                              hipStream_t stream) {
    const float* x    = (const float*)d_in[0];
    const int*   esrc = (const int*)  d_in[1];
    const int*   edst = (const int*)  d_in[2];
    const float* ew   = (const float*)d_in[3];
    const float* W    = (const float*)d_in[4];
    const float* b    = (const float*)d_in[5];
    float* out = (float*)d_out;

    char* ws = (char*)d_ws;

    if (ws_size >= WS_NEED) {
        unsigned* hidU  = (unsigned*)(ws + HIDB_OFF);
        int*      gcur1 = (int*)     (ws + G1_OFF);
        int*      ovfc  = (int*)     (ws + OVFC_OFF);
        int*      cnt2  = (int*)     (ws + CNT2_OFF);
        int4*     ovf   = (int4*)    (ws + OVF_OFF);
        uint2*    bkt1  = (uint2*)   (ws + BKT1_OFF);
        uint2*    bkt2  = (uint2*)   (ws + BKT2_OFF);
        float*    Wt    = (float*)   (ws + WT_OFF);

        // transpose W + zero control buffers
        srgnn_transpose<<<(DIM * DIM + 255) / 256, 256, 0, stream>>>(W, Wt, gcur1, ovfc);
        // GEMM: hidden(bf16) = x @ W^T + b
        srgnn_gemm2b<<<GEMM_BLOCKS, 256, 0, stream>>>(x, Wt, b, hidU);
        // two-level binning: 512-node super-buckets, then 32-node buckets
        srgnn_bin1<<<(N_EDGES + EPB1 - 1) / EPB1, 512, 0, stream>>>(
            esrc, edst, ew, gcur1, ovfc, ovf, bkt1);
        srgnn_bin2<<<SB_COUNT, 512, 0, stream>>>(gcur1, bkt1, cnt2, ovfc, ovf, bkt2);
        // block-per-bucket LDS sort + aggregate
        srgnn_agg_s32<<<NB, 256, 0, stream>>>(hidU, cnt2, bkt2, ovfc, ovf, out);
    } else {
        // fallback: atomic scatter
        float* hidden = (float*)ws;
        hipMemsetAsync(d_out, 0, (size_t)out_size * sizeof(float), stream);
        const int gemm_blocks = (N_NODES + 7) / 8;
        srgnn_gemm_bias<<<gemm_blocks, 256, 0, stream>>>(x, W, b, hidden);
        const long long work = (long long)N_EDGES * 25;
        const int scat_blocks = (int)((work + 255) / 256);
        srgnn_scatter_atomic<<<scat_blocks, 256, 0, stream>>>(hidden, esrc, edst, ew, out);
    }
}

// Round 12
// 80.505 us; speedup vs baseline: 1.3482x; 1.3482x over previous
//
#include <hip/hip_runtime.h>

#define N_NODES 50000
#define N_EDGES 800000
#define DIM 100

#define SB_COUNT 98         // super-buckets of 512 nodes (dst>>9)
#define CAP1     8704       // records per super-bucket region (mean 8163, +6 sigma)
#define NB       1563       // final buckets of 32 nodes (dst>>5)
#define CAPB     768        // records per final bucket (mean 512, +11 sigma)
#define OVF_CAP  4096
#define EPB1     2048       // edges per bin1 block -> 391 bin1 blocks
#define BIN1_BLOCKS 391
#define GEMM_BLOCKS 1250    // 50000/40
#define ROWS_PB  40
#define SPLIT2   8          // bin2 blocks per super-bucket -> 784 blocks

// ---------------- workspace layout (bytes) ----------------
#define HIDB_OFF  0u            // bf16 hidden, packed uint[50000*50]   10,000,000
#define G1_OFF    10000448u     // int gcur1[98]
#define OVFC_OFF  10000960u     // int ovf_cnt
#define CNT2_OFF  10001024u     // int cnt2[1568] (cursor == final count)
#define OVF_OFF   10007296u     // int4 ovf[4096]
#define BKT1_OFF  10072832u     // uint2 bkt1[98*8704]                   6,823,936
#define BKT2_OFF  16896768u     // uint2 bkt2[1568*768]                  9,633,792
#define WT_OFF    26530560u     // float Wt[100*100]                        40,000
#define WS_NEED   26570560u

// float->bf16 RNE helpers
__device__ inline unsigned bf16hi(float v) {            // bf16 in HIGH 16 bits
    unsigned u = __float_as_uint(v);
    u += 0x7FFFu + ((u >> 16) & 1u);
    return u & 0xFFFF0000u;
}
__device__ inline unsigned bf16pair(float lo, float hi) {
    unsigned ulo = __float_as_uint(lo); ulo += 0x7FFFu + ((ulo >> 16) & 1u);
    unsigned uhi = __float_as_uint(hi); uhi += 0x7FFFu + ((uhi >> 16) & 1u);
    return (ulo >> 16) | (uhi & 0xFFFF0000u);
}

// ---------------- transpose + control-buffer zeroing ----------------
__global__ __launch_bounds__(256) void srgnn_transpose(
    const float* __restrict__ W, float* __restrict__ Wt,
    int* __restrict__ gcur1, int* __restrict__ cnt2, int* __restrict__ ovfc)
{
    const unsigned i = blockIdx.x * 256u + threadIdx.x;
    if (i < DIM * DIM) {
        const int c = i / DIM, k = i - c * DIM;
        Wt[k * DIM + c] = W[i];
    }
    if (i < SB_COUNT) gcur1[i] = 0;
    if (i < SB_COUNT * 16) cnt2[i] = 0;
    if (i == 0) *ovfc = 0;
}

// ---------------- fused GEMM + bin1 (role-split, saves a dispatch) --------
// bid < 1250: gemm, 40 rows each. bid >= 1250: bin1, 2048 edges each into
// 98 super-buckets (runs of ~21 records = 2.6 lines, temporally local).
__global__ __launch_bounds__(256) void srgnn_gemm_bin1(
    const float* __restrict__ x, const float* __restrict__ Wt,
    const float* __restrict__ b, unsigned* __restrict__ hidU,
    const int* __restrict__ esrc, const int* __restrict__ edst,
    const float* __restrict__ ew, int* __restrict__ gcur1,
    int* __restrict__ ovfc, int4* __restrict__ ovf, uint2* __restrict__ bkt1)
{
    __shared__ float xs[ROWS_PB][DIM];   // 16 KB (gemm role)
    __shared__ int hist[SB_COUNT];       // bin1 role
    __shared__ int lcur[SB_COUNT];
    const int t = threadIdx.x;

    if (blockIdx.x < GEMM_BLOCKS) {
        // ---------------- GEMM ----------------
        const int row0 = blockIdx.x * ROWS_PB;

        for (int i = t; i < ROWS_PB * 25; i += 256) {
            const int r = i / 25, c4 = (i - r * 25) * 4;
            const float4 v = *reinterpret_cast<const float4*>(
                &x[(size_t)(row0 + r) * DIM + c4]);
            *reinterpret_cast<float4*>(&xs[r][c4]) = v;
        }
        __syncthreads();

        if (t < 250) {
            const int g  = t / 25;            // row group 0..9
            const int c4 = (t - g * 25) * 4;  // col chunk
            const float4 bv = *reinterpret_cast<const float4*>(&b[c4]);
            float4 a0 = bv, a1 = bv, a2 = bv, a3 = bv;

            #pragma unroll 4
            for (int k = 0; k < DIM; ++k) {
                const float4 wv = *reinterpret_cast<const float4*>(&Wt[k * DIM + c4]);
                const float x0 = xs[g     ][k];
                const float x1 = xs[g + 10][k];
                const float x2 = xs[g + 20][k];
                const float x3 = xs[g + 30][k];
                a0.x += x0 * wv.x; a0.y += x0 * wv.y; a0.z += x0 * wv.z; a0.w += x0 * wv.w;
                a1.x += x1 * wv.x; a1.y += x1 * wv.y; a1.z += x1 * wv.z; a1.w += x1 * wv.w;
                a2.x += x2 * wv.x; a2.y += x2 * wv.y; a2.z += x2 * wv.z; a2.w += x2 * wv.w;
                a3.x += x3 * wv.x; a3.y += x3 * wv.y; a3.z += x3 * wv.z; a3.w += x3 * wv.w;
            }
            const int u0 = c4 >> 1;
            uint2 p;
            p.x = bf16pair(a0.x, a0.y); p.y = bf16pair(a0.z, a0.w);
            *reinterpret_cast<uint2*>(&hidU[(size_t)(row0 + g     ) * 50 + u0]) = p;
            p.x = bf16pair(a1.x, a1.y); p.y = bf16pair(a1.z, a1.w);
            *reinterpret_cast<uint2*>(&hidU[(size_t)(row0 + g + 10) * 50 + u0]) = p;
            p.x = bf16pair(a2.x, a2.y); p.y = bf16pair(a2.z, a2.w);
            *reinterpret_cast<uint2*>(&hidU[(size_t)(row0 + g + 20) * 50 + u0]) = p;
            p.x = bf16pair(a3.x, a3.y); p.y = bf16pair(a3.z, a3.w);
            *reinterpret_cast<uint2*>(&hidU[(size_t)(row0 + g + 30) * 50 + u0]) = p;
        }
    } else {
        // ---------------- bin1 ----------------
        const int kb = blockIdx.x - GEMM_BLOCKS;     // 0..390
        const int e0 = kb * EPB1;

        for (int i = t; i < SB_COUNT; i += 256) hist[i] = 0;
        __syncthreads();

        int d[8];
        #pragma unroll
        for (int k = 0; k < 8; ++k) {
            const int e = e0 + t + k * 256;
            d[k] = (e < N_EDGES) ? edst[e] : -1;
            if (d[k] >= 0) atomicAdd(&hist[d[k] >> 9], 1);
        }
        __syncthreads();
        for (int i = t; i < SB_COUNT; i += 256)
            if (hist[i]) lcur[i] = atomicAdd(&gcur1[i], hist[i]);
        __syncthreads();
        #pragma unroll
        for (int k = 0; k < 8; ++k) {
            if (d[k] >= 0) {
                const int e = e0 + t + k * 256;
                const int s = esrc[e];
                const float w = ew[e];
                const int sb = d[k] >> 9;
                const int pos = atomicAdd(&lcur[sb], 1);
                if (pos < CAP1) {
                    bkt1[(size_t)sb * CAP1 + pos] =
                        make_uint2((unsigned)s | bf16hi(w), (unsigned)d[k]);
                } else {
                    const int op = atomicAdd(ovfc, 1);
                    if (op < OVF_CAP) ovf[op] = make_int4(d[k], s, __float_as_int(w), 0);
                }
            }
        }
    }
}

// ---------------- bin2: 8 blocks per super-bucket -> final buckets --------
// Block (sb, chunk) reads its ~1020-record contiguous slice twice (hist +
// place, coalesced, L2-resident) and appends one ~64-record (512B) run per
// final bucket via a single cnt2 cursor reservation -> zero write amp.
__global__ __launch_bounds__(256) void srgnn_bin2(
    const int* __restrict__ gcur1, const uint2* __restrict__ bkt1,
    int* __restrict__ cnt2, int* __restrict__ ovfc, int4* __restrict__ ovf,
    uint2* __restrict__ bkt2)
{
    __shared__ int histr[8][16];   // replicated local hist
    __shared__ int cur[16];        // global-reserved cursors
    const int t = threadIdx.x;
    const int sb = blockIdx.x >> 3;
    const int chunk = blockIdx.x & 7;
    const int rep = t & 7;

    int cnt = gcur1[sb];
    if (cnt > CAP1) cnt = CAP1;
    const int clen = (cnt + SPLIT2 - 1) >> 3;
    const int i0 = chunk * clen;
    int i1 = i0 + clen;
    if (i1 > cnt) i1 = cnt;

    if (t < 128) histr[t >> 4][t & 15] = 0;
    __syncthreads();

    for (int i = i0 + t; i < i1; i += 256) {
        const uint2 r = bkt1[(size_t)sb * CAP1 + i];
        atomicAdd(&histr[rep][(r.y >> 5) & 15], 1);
    }
    __syncthreads();

    if (t < 16) {
        int tot = 0;
        #pragma unroll
        for (int r = 0; r < 8; ++r) tot += histr[r][t];
        cur[t] = tot ? atomicAdd(&cnt2[sb * 16 + t], tot) : 0;
    }
    __syncthreads();

    for (int i = i0 + t; i < i1; i += 256) {
        const uint2 r = bkt1[(size_t)sb * CAP1 + i];
        const int j = (r.y >> 5) & 15;
        const int pos = atomicAdd(&cur[j], 1);
        if (pos < CAPB) {
            bkt2[(size_t)(sb * 16 + j) * CAPB + pos] = r;
        } else {
            const int op = atomicAdd(ovfc, 1);
            if (op < OVF_CAP)
                ovf[op] = make_int4((int)r.y, (int)(r.x & 0xFFFFu),
                                    (int)(r.x & 0xFFFF0000u), 0);
        }
    }
}

// ---------------- aggregate: block per 32-node bucket, LDS counting sort --
__global__ __launch_bounds__(256) void srgnn_agg_s32(
    const unsigned* __restrict__ hidU, const int* __restrict__ cnt2,
    const uint2* __restrict__ bkt2, const int* __restrict__ ovfc,
    const int4* __restrict__ ovf, float* __restrict__ out)
{
    __shared__ uint2    recs[CAPB];     // 6144 B
    __shared__ unsigned srt[CAPB];      // 3072 B
    __shared__ int nh[32], sc[32], cur[32];

    const int t = threadIdx.x;
    const int bq = blockIdx.x;
    int cntb = cnt2[bq];
    if (cntb > CAPB) cntb = CAPB;

    if (t < 32) nh[t] = 0;
    __syncthreads();
    for (int i = t; i < cntb; i += 256) {
        const uint2 r = bkt2[(size_t)bq * CAPB + i];
        recs[i] = r;
        atomicAdd(&nh[r.y & 31], 1);
    }
    __syncthreads();
    if (t < 32) sc[t] = nh[t];
    __syncthreads();
    for (int ofs = 1; ofs < 32; ofs <<= 1) {         // Hillis-Steele inclusive
        int a = 0;
        if (t < 32 && t >= ofs) a = sc[t - ofs];
        __syncthreads();
        if (t < 32) sc[t] += a;
        __syncthreads();
    }
    if (t < 32) cur[t] = sc[t] - nh[t];
    __syncthreads();
    for (int i = t; i < cntb; i += 256) {
        const uint2 r = recs[i];
        const int pos = atomicAdd(&cur[r.y & 31], 1);
        srt[pos] = r.x;                              // src | bf16(w)<<16
    }
    __syncthreads();

    int oc = *ovfc;                                  // ~always 0
    if (oc > OVF_CAP) oc = OVF_CAP;
    const int lane = t & 63;
    const int wid  = t >> 6;                         // 4 waves
    const bool active = (lane < 50);

    for (int q = 0; q < 8; ++q) {
        const int n  = wid * 8 + q;                  // 4 waves x 8 = 32 nodes
        const int s1 = sc[n];
        const int s0 = s1 - nh[n];
        float2 acc = make_float2(0.f, 0.f);

        int p = s0;
        for (; p + 8 <= s1; p += 8) {                // 8-deep MLP
            unsigned r[8], h[8];
            #pragma unroll
            for (int j = 0; j < 8; ++j) r[j] = srt[p + j];
            if (active) {
                #pragma unroll
                for (int j = 0; j < 8; ++j)
                    h[j] = hidU[(size_t)(r[j] & 0xFFFFu) * 50 + lane];
                #pragma unroll
                for (int j = 0; j < 8; ++j) {
                    const float wj = __uint_as_float(r[j] & 0xFFFF0000u);
                    acc.x += wj * __uint_as_float(h[j] << 16);
                    acc.y += wj * __uint_as_float(h[j] & 0xFFFF0000u);
                }
            }
        }
        for (; p < s1; ++p) {
            const unsigned r = srt[p];
            const float wi = __uint_as_float(r & 0xFFFF0000u);
            if (active) {
                const unsigned h = hidU[(size_t)(r & 0xFFFFu) * 50 + lane];
                acc.x += wi * __uint_as_float(h << 16);
                acc.y += wi * __uint_as_float(h & 0xFFFF0000u);
            }
        }

        const int ng = bq * 32 + n;
        if (oc > 0) {                                // ultra-rare overflow scan
            for (int i = 0; i < oc; ++i) {
                const int4 v = ovf[i];
                if (v.x == ng && active) {
                    const unsigned h = hidU[(size_t)v.y * 50 + lane];
                    const float wi = __uint_as_float((unsigned)v.z);
                    acc.x += wi * __uint_as_float(h << 16);
                    acc.y += wi * __uint_as_float(h & 0xFFFF0000u);
                }
            }
        }
        if (ng < N_NODES && active)
            *reinterpret_cast<float2*>(&out[(size_t)ng * DIM + 2 * lane]) = acc;
    }
}

// ---------------- fallback (atomic scatter, needs only 20MB ws) ----------
__global__ __launch_bounds__(256) void srgnn_gemm_bias(
    const float* __restrict__ x, const float* __restrict__ W,
    const float* __restrict__ b, float* __restrict__ hidden)
{
    __shared__ float Wt[DIM][DIM + 4];
    __shared__ float bs[DIM];
    __shared__ float xs[8][DIM];
    const int t = threadIdx.x;
    for (int i = t; i < DIM * DIM; i += 256) {
        int c = i / DIM, k = i - c * DIM;
        Wt[k][c] = W[i];
    }
    if (t < DIM) bs[t] = b[t];
    const int row0 = blockIdx.x * 8;
    for (int i = t; i < 8 * DIM; i += 256) {
        int r = i / DIM, k = i - r * DIM;
        int row = row0 + r;
        xs[r][k] = (row < N_NODES) ? x[row * DIM + k] : 0.0f;
    }
    __syncthreads();
    if (t < 200) {
        const int r  = t / 25;
        const int c4 = (t - r * 25) * 4;
        float acc0 = bs[c4 + 0], acc1 = bs[c4 + 1], acc2 = bs[c4 + 2], acc3 = bs[c4 + 3];
        for (int k = 0; k < DIM; ++k) {
            const float xv = xs[r][k];
            const float4 wv = *reinterpret_cast<const float4*>(&Wt[k][c4]);
            acc0 += xv * wv.x; acc1 += xv * wv.y; acc2 += xv * wv.z; acc3 += xv * wv.w;
        }
        const int row = row0 + r;
        if (row < N_NODES)
            *reinterpret_cast<float4*>(&hidden[row * DIM + c4]) =
                make_float4(acc0, acc1, acc2, acc3);
    }
}

__global__ __launch_bounds__(256) void srgnn_scatter_atomic(
    const float* __restrict__ hidden, const int* __restrict__ esrc,
    const int* __restrict__ edst, const float* __restrict__ ew,
    float* __restrict__ out)
{
    const unsigned gid = blockIdx.x * 256u + threadIdx.x;
    const unsigned e = gid / 25u;
    const unsigned j = gid - e * 25u;
    if (e >= N_EDGES) return;
    const int   s  = esrc[e];
    const int   d  = edst[e];
    const float wt = ew[e];
    const float4 h = *reinterpret_cast<const float4*>(&hidden[(size_t)s * DIM + j * 4]);
    float* op = &out[(size_t)d * DIM + j * 4];
    atomicAdd(op + 0, h.x * wt);
    atomicAdd(op + 1, h.y * wt);
    atomicAdd(op + 2, h.z * wt);
    atomicAdd(op + 3, h.w * wt);
}

extern "C" void kernel_launch(void* const* d_in, const int* in_sizes, int n_in,
                              void* d_out, int out_size, void* d_ws, size_t ws_size,
                              hipStream_t stream) {
    const float* x    = (const float*)d_in[0];
    const int*   esrc = (const int*)  d_in[1];
    const int*   edst = (const int*)  d_in[2];
    const float* ew   = (const float*)d_in[3];
    const float* W    = (const float*)d_in[4];
    const float* b    = (const float*)d_in[5];
    float* out = (float*)d_out;

    char* ws = (char*)d_ws;

    if (ws_size >= WS_NEED) {
        unsigned* hidU  = (unsigned*)(ws + HIDB_OFF);
        int*      gcur1 = (int*)     (ws + G1_OFF);
        int*      ovfc  = (int*)     (ws + OVFC_OFF);
        int*      cnt2  = (int*)     (ws + CNT2_OFF);
        int4*     ovf   = (int4*)    (ws + OVF_OFF);
        uint2*    bkt1  = (uint2*)   (ws + BKT1_OFF);
        uint2*    bkt2  = (uint2*)   (ws + BKT2_OFF);
        float*    Wt    = (float*)   (ws + WT_OFF);

        // transpose W + zero control buffers
        srgnn_transpose<<<(DIM * DIM + 255) / 256, 256, 0, stream>>>(
            W, Wt, gcur1, cnt2, ovfc);
        // fused: GEMM (1250 blocks) + bin1 (391 blocks, 98 super-buckets)
        srgnn_gemm_bin1<<<GEMM_BLOCKS + BIN1_BLOCKS, 256, 0, stream>>>(
            x, Wt, b, hidU, esrc, edst, ew, gcur1, ovfc, ovf, bkt1);
        // bin2: 8 blocks per super-bucket -> 32-node buckets, long runs
        srgnn_bin2<<<SB_COUNT * SPLIT2, 256, 0, stream>>>(
            gcur1, bkt1, cnt2, ovfc, ovf, bkt2);
        // block-per-bucket LDS sort + aggregate
        srgnn_agg_s32<<<NB, 256, 0, stream>>>(hidU, cnt2, bkt2, ovfc, ovf, out);
    } else {
        // fallback: atomic scatter
        float* hidden = (float*)ws;
        hipMemsetAsync(d_out, 0, (size_t)out_size * sizeof(float), stream);
        const int gemm_blocks = (N_NODES + 7) / 8;
        srgnn_gemm_bias<<<gemm_blocks, 256, 0, stream>>>(x, W, b, hidden);
        const long long work = (long long)N_EDGES * 25;
        const int scat_blocks = (int)((work + 255) / 256);
        srgnn_scatter_atomic<<<scat_blocks, 256, 0, stream>>>(hidden, esrc, edst, ew, out);
    }
}